// Round 5
// baseline (648.322 us; speedup 1.0000x reference)
//
#include <hip/hip_runtime.h>
#include <hip/hip_fp16.h>
#include <stdint.h>

// Problem constants (B, S, H from the reference)
#define B_SZ 32
#define S_SZ 2048
#define H_SZ 1024
#define M_SZ (B_SZ * S_SZ)   // 65536 rows of the big GEMM

typedef _Float16 half8 __attribute__((ext_vector_type(8)));
typedef float floatx4 __attribute__((ext_vector_type(4)));

struct h4 { _Float16 x, y, z, w; };   // 8-byte packed fp16x4

// ---------------- fp32 -> fp16 convert (Wk only) ----------------
__global__ __launch_bounds__(256) void convert_f32_to_f16(
    const float* __restrict__ in, h4* __restrict__ out, int n4) {
  int i = blockIdx.x * blockDim.x + threadIdx.x;
  int stride = gridDim.x * blockDim.x;
  const float4* in4 = (const float4*)in;
  for (; i < n4; i += stride) {
    float4 f = in4[i];
    h4 o;
    o.x = (_Float16)f.x; o.y = (_Float16)f.y;
    o.z = (_Float16)f.z; o.w = (_Float16)f.w;
    out[i] = o;
  }
}

// ---------------- query = hidden @ Wq^T  (fp32 exact, tiny) ----------------
__global__ __launch_bounds__(256) void query_kernel(
    const float* __restrict__ hidden, const float* __restrict__ Wq,
    float* __restrict__ q) {
  int t = blockIdx.x * blockDim.x + threadIdx.x;   // 32768 threads
  int b = t & 31;
  int n = t >> 5;
  const float4* h4p = (const float4*)(hidden + (size_t)b * H_SZ);
  const float4* w4p = (const float4*)(Wq + (size_t)n * H_SZ);
  float acc = 0.f;
  #pragma unroll 4
  for (int i = 0; i < H_SZ / 4; ++i) {
    float4 h = h4p[i], w = w4p[i];
    acc = fmaf(h.x, w.x, acc);
    acc = fmaf(h.y, w.y, acc);
    acc = fmaf(h.z, w.z, acc);
    acc = fmaf(h.w, w.w, acc);
  }
  q[(size_t)b * H_SZ + n] = acc;
}

// ---------------- async global->LDS, 16B per lane (per-lane SOURCE address) ----------------
__device__ __forceinline__ void gl_lds16(const void* g, void* l) {
  __builtin_amdgcn_global_load_lds(
      (const __attribute__((address_space(1))) void*)g,
      (__attribute__((address_space(3))) void*)l,
      16, 0, 0);
}

__device__ __forceinline__ float fast_tanh(float x) {
  float ax = fabsf(x);
  float e = __expf(ax * -2.0f);
  float t = (1.0f - e) / (1.0f + e);
  return copysignf(t, x);
}

// ---------------- fused fp32->fp16 + keys-GEMM + tanh + v-dot ----------------
// C[m,n] = sum_k A[m,k] * Bt[n,k]
// partial[bn][m] = sum_{n in col-tile} v[n]*tanh(q[b,n]+C[m,n])
//
// Round-5 structure (counted-vmcnt depth-2 pipeline, T3/T4-style):
//  - stage tile t+2 while computing tile t.  Bs has 3 buffers (DMA 2 ahead),
//    As has 2 buffers (ds_write 1 ahead), A-regs 2 sets.
//  - Barrier = asm lgkmcnt(0) + raw s_barrier.  NO vmcnt drain in the loop:
//    per iteration the issue order is FORCED (empty asm memory fence) to
//    B(t+2) THEN A(t+2).  writeA(t+1) reads the A(t+1) regs, so the compiler
//    MUST emit a vmcnt wait draining through A(t+1); FIFO vmcnt semantics
//    then guarantee B(t+1) (issued earlier) has landed before the barrier.
//    Loads for t+2 (6 vm ops/wave) stay in flight ACROSS the barrier.
//  - Full unroll (32 iters) keeps all %2/%3 buffer and reg-set indices
//    compile-time (rule #20: no scratch).
//  - T5: s_setprio(1) around the MFMA cluster.
//  - LDS 41 KB -> 3 blocks/CU; __launch_bounds__(256,3).
#define TILE 128
#define BK 32
#define NT (H_SZ / BK)   // 32 K-tiles

__global__ __launch_bounds__(256, 3) void fused_keys_kernel(
    const float* __restrict__ A,       // enc fp32, M_SZ x H_SZ
    const _Float16* __restrict__ Bt,   // Wk fp16, H_SZ x H_SZ
    const float* __restrict__ q,       // B_SZ x H_SZ (fp32)
    const float* __restrict__ v,       // H_SZ
    float* __restrict__ partial)       // 8 x M_SZ
{
  __shared__ __align__(16) _Float16 As[2][TILE * BK];   // 2 x 8 KB fp16
  __shared__ __align__(16) _Float16 Bs[3][TILE * BK];   // 3 x 8 KB fp16
  __shared__ float q_l[TILE];
  __shared__ float v_l[TILE];

  const int tid  = threadIdx.x;
  const int w    = tid >> 6;       // wave 0..3
  const int lane = tid & 63;

  // XCD-aware bijective swizzle: the 8 bn-blocks sharing one A row-tile all
  // land on the same XCD. nwg = 4096, 4096 % 8 == 0 -> bijective.
  const int hw   = blockIdx.x;
  const int xcd  = hw & 7;
  const int slot = hw >> 3;
  const int bn   = slot & 7;
  const int bm   = ((slot >> 3) << 3) | xcd;   // bm & 7 == xcd

  const int R0   = bm * TILE;         // global row base (b*S + s)
  const int C0   = bn * TILE;         // global col base (n dim of H)
  const int bidx = R0 >> 11;          // batch index; uniform (2048 % 128 == 0)

  if (tid < TILE) {
    q_l[tid] = q[(size_t)bidx * H_SZ + C0 + tid];
    v_l[tid] = v[C0 + tid];
  }

  const int cL   = lane & 15, quad = lane >> 4;
  const int sB   = (cL >> 1) & 3;  // read swizzle key (same involution as writes)

  floatx4 acc[2][8];
  #pragma unroll
  for (int m = 0; m < 2; ++m)
    #pragma unroll
    for (int n = 0; n < 8; ++n)
      acc[m][n] = (floatx4){0.f, 0.f, 0.f, 0.f};

  // ---- A reg-staging lane decomposition: 2 lanes per row, 16 floats each ----
  const int arow = w * 32 + (lane >> 1);  // row this lane stages
  const int ah   = lane & 1;              // which 16-float half of the 32-float row
  const int akey = (lane >> 2) & 3;       // == (arow>>1)&3
  const int ap0  = (2 * ah)     ^ akey;   // phys chunk for floats [16ah, 16ah+8)
  const int ap1  = (2 * ah + 1) ^ akey;   // phys chunk for floats [16ah+8, 16ah+16)
  const float* Asrc = A + (size_t)(R0 + arow) * H_SZ + ah * 16;

  // ---- B staging lane decomposition (global_load_lds, source-swizzled) ----
  const int brow_l = lane >> 2;   // 4 lanes cover one 64B fp16 row
  const int bp     = lane & 3;    // physical 16B chunk 0..3
  const _Float16* Bblk = Bt + (size_t)C0 * H_SZ;

  float4 ar[2][4];                // 2 in-flight A reg sets (const-indexed only)

  // ---- issue B global_load_lds for K-tile kt2 into Bs[b] ----
  auto stageB = [&](int kt2, int b) {
    const int kof = kt2 * BK;
    #pragma unroll
    for (int j = 0; j < 2; ++j) {
      const int row = w * 32 + j * 16 + brow_l;
      const int cg  = bp ^ ((row >> 1) & 3);
      gl_lds16(Bblk + (size_t)row * H_SZ + kof + cg * 8,
               (char*)&Bs[b][0] + (w * 128 + j * 64) * 16);
    }
  };

  // ---- load A fp32 for K-tile kt2 into reg set s ----
  auto loadA = [&](int kt2, int s) {
    const float4* p = (const float4*)(Asrc + kt2 * BK);
    ar[s][0] = p[0]; ar[s][1] = p[1]; ar[s][2] = p[2]; ar[s][3] = p[3];
  };

  // ---- cvt reg set s -> fp16, swizzled ds_write into As[b] ----
  auto writeA = [&](int s, int b) {
    half8 h0 = (half8){(_Float16)ar[s][0].x, (_Float16)ar[s][0].y, (_Float16)ar[s][0].z, (_Float16)ar[s][0].w,
                       (_Float16)ar[s][1].x, (_Float16)ar[s][1].y, (_Float16)ar[s][1].z, (_Float16)ar[s][1].w};
    half8 h1 = (half8){(_Float16)ar[s][2].x, (_Float16)ar[s][2].y, (_Float16)ar[s][2].z, (_Float16)ar[s][2].w,
                       (_Float16)ar[s][3].x, (_Float16)ar[s][3].y, (_Float16)ar[s][3].z, (_Float16)ar[s][3].w};
    _Float16* dst = &As[b][arow * BK];
    *(half8*)(dst + ap0 * 8) = h0;
    *(half8*)(dst + ap1 * 8) = h1;
  };

  // ---- compute one K-step from As[ab], Bs[bb] ----
  auto compute = [&](int ab, int bb) {
    half8 af[2], bf[8];
    #pragma unroll
    for (int m = 0; m < 2; ++m) {
      const int r = w * 32 + m * 16 + cL;
      af[m] = *(const half8*)(&As[ab][r * BK] + ((quad ^ sB) << 3));
    }
    #pragma unroll
    for (int n = 0; n < 8; ++n) {
      const int r = n * 16 + cL;
      bf[n] = *(const half8*)(&Bs[bb][r * BK] + ((quad ^ sB) << 3));
    }
    __builtin_amdgcn_s_setprio(1);
    #pragma unroll
    for (int m = 0; m < 2; ++m)
      #pragma unroll
      for (int n = 0; n < 8; ++n)
        acc[m][n] = __builtin_amdgcn_mfma_f32_16x16x32_f16(af[m], bf[n], acc[m][n], 0, 0, 0);
    __builtin_amdgcn_s_setprio(0);
  };

  // ---- prologue: tiles 0 and 1 in flight; tile 0 made LDS-ready ----
  stageB(0, 0);
  asm volatile("" ::: "memory");       // force issue order: B(0) before A(0)
  loadA(0, 0);
  stageB(1, 1);
  asm volatile("" ::: "memory");       // B(1) before A(1)
  loadA(1, 1);
  writeA(0, 0);                        // auto vmcnt drains thru A(0) => B(0) done
  asm volatile("s_waitcnt lgkmcnt(0)" ::: "memory");
  __builtin_amdgcn_s_barrier();        // tile 0 ready; tile 1 loads still in flight

  // ---- main loop: compute(t) while tiles t+1 (LDS) and t+2 (flight) pend ----
  #pragma unroll
  for (int t = 0; t < NT; ++t) {
    if (t + 2 < NT) {
      stageB(t + 2, (t + 2) % 3);
      asm volatile("" ::: "memory");   // B(t+2) issued before A(t+2)
      loadA(t + 2, t & 1);
    }
    compute(t & 1, t % 3);
    if (t + 1 < NT) {
      writeA((t + 1) & 1, (t + 1) & 1);  // auto vmcnt thru A(t+1) => B(t+1) done
      asm volatile("s_waitcnt lgkmcnt(0)" ::: "memory");
      __builtin_amdgcn_s_barrier();      // t+2 loads remain in flight
    }
  }

  // ---- epilogue: v[n]*tanh(q+c), each wave owns its 32 rows ----
  float qv[8], vv[8];
  #pragma unroll
  for (int n = 0; n < 8; ++n) {
    const int col = n * 16 + cL;
    qv[n] = q_l[col];
    vv[n] = v_l[col];
  }
  // C/D layout: col = lane&15, row = quad*4 + reg  [m89-verified]
  #pragma unroll
  for (int m = 0; m < 2; ++m) {
    #pragma unroll
    for (int r = 0; r < 4; ++r) {
      float s = 0.f;
      #pragma unroll
      for (int n = 0; n < 8; ++n)
        s += vv[n] * fast_tanh(qv[n] + acc[m][n][r]);
      // reduce across the 16 lanes (cL) sharing this row
      s += __shfl_xor(s, 1);
      s += __shfl_xor(s, 2);
      s += __shfl_xor(s, 4);
      s += __shfl_xor(s, 8);
      if (cL == 0)
        partial[(size_t)bn * M_SZ + R0 + w * 32 + m * 16 + quad * 4 + r] = s;
    }
  }
}

// ---------------- masked softmax over S per batch row ----------------
__global__ __launch_bounds__(256) void softmax_kernel(
    const float* __restrict__ partial, const int* __restrict__ lengths,
    float* __restrict__ out) {
  __shared__ float wred[4];
  __shared__ float wsum[4];
  const int b = blockIdx.x;
  const int tid = threadIdx.x;
  const int len = lengths[b];

  float lg[8];
  #pragma unroll
  for (int i = 0; i < 8; ++i) {
    const int s = tid + i * 256;
    const size_t row = (size_t)b * S_SZ + s;
    float l = 0.f;
    #pragma unroll
    for (int nt = 0; nt < 8; ++nt) l += partial[(size_t)nt * M_SZ + row];
    lg[i] = (s < len) ? l : -INFINITY;
  }

  float mx = lg[0];
  #pragma unroll
  for (int i = 1; i < 8; ++i) mx = fmaxf(mx, lg[i]);
  #pragma unroll
  for (int off = 32; off; off >>= 1) mx = fmaxf(mx, __shfl_xor(mx, off));
  if ((tid & 63) == 0) wred[tid >> 6] = mx;
  __syncthreads();
  mx = fmaxf(fmaxf(wred[0], wred[1]), fmaxf(wred[2], wred[3]));

  float pe[8];
  float sum = 0.f;
  #pragma unroll
  for (int i = 0; i < 8; ++i) {
    float e = (lg[i] == -INFINITY) ? 0.f : __expf(lg[i] - mx);
    pe[i] = e;
    sum += e;
  }
  #pragma unroll
  for (int off = 32; off; off >>= 1) sum += __shfl_xor(sum, off);
  if ((tid & 63) == 0) wsum[tid >> 6] = sum;
  __syncthreads();
  sum = wsum[0] + wsum[1] + wsum[2] + wsum[3];
  const float inv = 1.0f / sum;

  #pragma unroll
  for (int i = 0; i < 8; ++i) {
    const int s = tid + i * 256;
    out[(size_t)b * S_SZ + s] = pe[i] * inv;
  }
}

extern "C" void kernel_launch(void* const* d_in, const int* in_sizes, int n_in,
                              void* d_out, int out_size, void* d_ws, size_t ws_size,
                              hipStream_t stream) {
  const float* hidden  = (const float*)d_in[0];  // (32, 1024)
  const float* enc     = (const float*)d_in[1];  // (32, 2048, 1024)
  const int*   lengths = (const int*)d_in[2];    // (32,)
  const float* Wq      = (const float*)d_in[3];  // (1024, 1024)
  const float* Wk      = (const float*)d_in[4];  // (1024, 1024)
  const float* v       = (const float*)d_in[5];  // (1024,)
  float* out = (float*)d_out;                    // (32, 2048) fp32

  // ws layout: B16 (2 MB) | q (128 KB) | partial (2 MB)   — 4.2 MB total
  char* ws = (char*)d_ws;
  _Float16* B16     = (_Float16*)ws;
  float*    q       = (float*)(ws + 2097152);
  float*    partial = (float*)(ws + 2097152 + 131072);

  convert_f32_to_f16<<<1024, 256, 0, stream>>>(Wk, (h4*)B16, (H_SZ * H_SZ) / 4);
  query_kernel<<<128, 256, 0, stream>>>(hidden, Wq, q);
  fused_keys_kernel<<<(M_SZ / TILE) * (H_SZ / TILE), 256, 0, stream>>>(enc, B16, q, v, partial);
  softmax_kernel<<<B_SZ, 256, 0, stream>>>(partial, lengths, out);
}